// Round 4
// baseline (196.039 us; speedup 1.0000x reference)
//
#include <hip/hip_runtime.h>
#include <stdint.h>

typedef float f32x2 __attribute__((ext_vector_type(2)));
typedef float f32x4 __attribute__((ext_vector_type(4)));

#define ROWS   32
#define TILE_F (ROWS * 310)       // 9920 floats = 39680 B, 16B-aligned flat tile

__device__ __forceinline__ f32x2 leaky2(f32x2 v) {
    return __builtin_elementwise_max(v, v * 0.01f);
}

// global->LDS direct, 16 B per lane. LDS operand is wave-uniform base;
// HW adds lane*16. Global operand is per-lane.
__device__ __forceinline__ void gload16(const float* g, float* l) {
    auto gp = reinterpret_cast<const float __attribute__((address_space(1)))*>(
        reinterpret_cast<uintptr_t>(g));
    auto lp = reinterpret_cast<float __attribute__((address_space(3)))*>(
        reinterpret_cast<uintptr_t>(l));
    __builtin_amdgcn_global_load_lds(gp, lp, 16, 0, 0);
}

__global__ __launch_bounds__(128, 4) void gen_mlp_flat(
    const float* __restrict__ x, const float* __restrict__ data_t,
    const float* __restrict__ W1, const float* __restrict__ b1,
    const float* __restrict__ W2, const float* __restrict__ b2,
    const float* __restrict__ W3, const float* __restrict__ b3,
    float* __restrict__ out)
{
    __shared__ float lds[TILE_F];   // 39680 B -> 4 blocks/CU (8 waves/CU)

    const int t    = threadIdx.x;
    const int lane = t & 63;
    const int w    = t >> 6;               // wave 0 or 1
    const int r0   = blockIdx.x * ROWS;

    // ---- stage the whole 32-row tile as a flat 16B-aligned copy ----
    // 39680 B = 38 full w16 instrs (1024 B each) + 768 B tail (48 lanes)
    const float* xt = x + (size_t)r0 * 310;
    if (w == 0) {
        #pragma unroll
        for (int i = 0; i < 19; ++i)
            gload16(xt + lane * 4 + i * 256, lds + i * 256);
    } else {
        #pragma unroll
        for (int i = 19; i < 38; ++i)
            gload16(xt + lane * 4 + i * 256, lds + i * 256);
        if (lane < 48)
            gload16(xt + 38 * 256 + lane * 4, lds + 38 * 256);
    }

    // ---- T14: issue data_t loads now; consumed after coeffs are known ----
    const f32x4* dt4 = (const f32x4*)data_t + (size_t)blockIdx.x * (ROWS * 25);
    f32x4 tv[7];
    #pragma unroll
    for (int i = 0; i < 7; ++i) {
        const int idx = i * 128 + t;
        if (idx < ROWS * 25) tv[i] = dt4[idx];
    }

    __syncthreads();   // barrier drain: tile + tv resident

    // ---- L1: wave w handles k-half w (0:[0,156) 78 pairs, 1:[156,310) 77)
    // for all 32 rows; lanes 32-63 mirror 0-31 (free in SIMT time).
    // W1 index is wave-uniform (SGPR via readfirstlane) -> s_load broadcast.
    const int row = lane & 31;
    const int qs  = __builtin_amdgcn_readfirstlane(w == 0 ? 0 : 156);
    const float* xr = lds + row * 310 + qs;     // 8B-aligned
    const float* Wq = W1 + qs * 10;

    f32x2 acc[5] = {{0.f,0.f},{0.f,0.f},{0.f,0.f},{0.f,0.f},{0.f,0.f}};
    #pragma unroll
    for (int i = 0; i < 77; ++i) {
        f32x2 xk = *(const f32x2*)(xr + 2 * i);           // ds_read_b64
        const f32x2* wp0 = (const f32x2*)(Wq + (2 * i) * 10);
        const f32x2* wp1 = (const f32x2*)(Wq + (2 * i + 1) * 10);
        #pragma unroll
        for (int j = 0; j < 5; ++j) acc[j] += (f32x2){xk.x, xk.x} * wp0[j];
        #pragma unroll
        for (int j = 0; j < 5; ++j) acc[j] += (f32x2){xk.y, xk.y} * wp1[j];
    }
    if (qs == 0) {   // half 0 has one extra pair (k=154,155) — scalar branch
        f32x2 xk = *(const f32x2*)(xr + 154);
        const f32x2* wp0 = (const f32x2*)(Wq + 1540);
        const f32x2* wp1 = (const f32x2*)(Wq + 1550);
        #pragma unroll
        for (int j = 0; j < 5; ++j) acc[j] += (f32x2){xk.x, xk.x} * wp0[j];
        #pragma unroll
        for (int j = 0; j < 5; ++j) acc[j] += (f32x2){xk.y, xk.y} * wp1[j];
    }

    __syncthreads();            // all tile reads done -> safe to alias
    if (lane < 32) {            // partials[row][w][10] at lds[0..640)
        float* pb = lds + (row * 2 + w) * 10;
        #pragma unroll
        for (int j = 0; j < 5; ++j) *(f32x2*)(pb + 2 * j) = acc[j];
    }
    __syncthreads();

    // ---- reduce halves + bias + leaky -> h1[10] (every thread, own row) ----
    float h1[10];
    {
        const float* pa = lds + (row * 2 + 0) * 10;
        const float* pc = lds + (row * 2 + 1) * 10;
        #pragma unroll
        for (int j = 0; j < 5; ++j) {
            f32x2 s = *(const f32x2*)(pa + 2 * j) + *(const f32x2*)(pc + 2 * j)
                    + *(const f32x2*)(b1 + 2 * j);
            f32x2 v = leaky2(s);
            h1[2 * j] = v.x; h1[2 * j + 1] = v.y;
        }
    }

    // ---- L2 (10->128) + L3 (128->2), uniform weights (s_load), pk math ----
    f32x2 p = {0.f, 0.f};
    #pragma unroll
    for (int jg = 0; jg < 16; ++jg) {
        f32x2 hh[4];
        #pragma unroll
        for (int m = 0; m < 4; ++m)
            hh[m] = *(const f32x2*)(b2 + jg * 8 + 2 * m);
        #pragma unroll
        for (int k = 0; k < 10; ++k) {
            const f32x2 hs = {h1[k], h1[k]};
            const f32x2* w2p = (const f32x2*)(W2 + k * 128 + jg * 8);
            #pragma unroll
            for (int m = 0; m < 4; ++m)
                hh[m] += hs * w2p[m];
        }
        #pragma unroll
        for (int m = 0; m < 4; ++m) {
            f32x2 v = leaky2(hh[m]);
            const int j0 = jg * 8 + 2 * m;
            f32x2 w3a = *(const f32x2*)(W3 + j0 * 2);
            f32x2 w3b = *(const f32x2*)(W3 + j0 * 2 + 2);
            p += (f32x2){v.x, v.x} * w3a;
            p += (f32x2){v.y, v.y} * w3b;
        }
    }
    p = leaky2(p + *(const f32x2*)b3);

    // ---- stash coeffs (disjoint from partials region), then epilogue ----
    if (t < 32) *(f32x2*)(lds + 640 + 2 * row) = p;
    __syncthreads();

    f32x4* o4 = (f32x4*)out + (size_t)blockIdx.x * (ROWS * 25);
    #pragma unroll
    for (int i = 0; i < 7; ++i) {
        const int idx = i * 128 + t;
        if (idx < ROWS * 25) {
            const int r = idx / 25;                       // 0..31
            f32x2 cc = *(const f32x2*)(lds + 640 + 2 * r);
            f32x4 tt = tv[i];
            f32x4 u  = tt * cc.y + cc.x;                  // c0 + c1*t
            o4[idx]  = tt * u;                            // t*(c0 + c1*t)
        }
    }
}

extern "C" void kernel_launch(void* const* d_in, const int* in_sizes, int n_in,
                              void* d_out, int out_size, void* d_ws, size_t ws_size,
                              hipStream_t stream) {
    const float* x      = (const float*)d_in[0];
    const float* data_t = (const float*)d_in[1];
    const float* W1     = (const float*)d_in[2];
    const float* b1     = (const float*)d_in[3];
    const float* W2     = (const float*)d_in[4];
    const float* b2     = (const float*)d_in[5];
    const float* W3     = (const float*)d_in[6];
    const float* b3     = (const float*)d_in[7];
    float* out = (float*)d_out;

    // 4096 blocks x 128 threads, 32 rows/block; 4 blocks/CU resident
    gen_mlp_flat<<<4096, 128, 0, stream>>>(x, data_t, W1, b1, W2, b2, W3, b3, out);
}

// Round 5
// 78.621 us; speedup vs baseline: 2.4935x; 2.4935x over previous
//
#include <hip/hip_runtime.h>
#include <stdint.h>

typedef float f32x2 __attribute__((ext_vector_type(2)));
typedef float f32x4 __attribute__((ext_vector_type(4)));

#define TROWS   64
#define TILE_F  19840          // floats per tile (64 rows x 310)
#define NTPB    8              // tiles per block
#define LDS_BYTES 161280       // 2*79360 + 2048 (p-partials) + 512 (coeffs)

__device__ __forceinline__ float leaky(float v) { return fmaxf(v, 0.01f * v); }
__device__ __forceinline__ f32x2 leaky2(f32x2 v) {
    return __builtin_elementwise_max(v, v * 0.01f);
}
__device__ __forceinline__ float rlane(float v, int l) {
    return __uint_as_float(__builtin_amdgcn_readlane(__float_as_uint(v), l));
}

// global->LDS direct, 16 B per lane (1 KB per wave-instr). LDS base uniform.
__device__ __forceinline__ void gload16(const float* g, float* l) {
    auto gp = reinterpret_cast<const float __attribute__((address_space(1)))*>(
        reinterpret_cast<uintptr_t>(g));
    auto lp = reinterpret_cast<float __attribute__((address_space(3)))*>(
        reinterpret_cast<uintptr_t>(l));
    __builtin_amdgcn_global_load_lds(gp, lp, 16, 0, 0);
}

// Stage one wave-quarter of a tile: 4960 floats = 19 full w16 + 96-float tail.
__device__ __forceinline__ void stage_quarter(const float* src, float* dst, int lane) {
    #pragma unroll
    for (int i = 0; i < 19; ++i) gload16(src + i * 256, dst + i * 256);
    if (lane < 24) gload16(src + 19 * 256, dst + 19 * 256);
}

__global__ __launch_bounds__(256) void gen_mlp_r5(
    const float* __restrict__ x, const float* __restrict__ data_t,
    const float* __restrict__ W1, const float* __restrict__ b1,
    const float* __restrict__ W2, const float* __restrict__ b2,
    const float* __restrict__ W3, const float* __restrict__ b3,
    float* __restrict__ out)
{
    extern __shared__ float lds[];

    const int t    = threadIdx.x;
    const int lane = t & 63;
    const int row  = lane;                                   // L1: lane = row
    const int wq   = __builtin_amdgcn_readfirstlane(t >> 6); // wave 0..3
    const int k0   = wq * 78;                                // k-quarter base
    const int KQ   = (wq == 3) ? 76 : 78;

    // ---- one-time weight preloads into lane-distributed VGPRs ----
    float Wq[13];                         // W1 quarter: m=(k-k0)*10+j -> reg m>>6, lane m&63
    {
        const int cnt = (wq == 3) ? 760 : 780;
        #pragma unroll
        for (int i = 0; i < 13; ++i) {
            int m = i * 64 + lane;
            Wq[i] = (m < cnt) ? W1[wq * 780 + m] : 0.f;
        }
    }
    float W2r[5];                         // W2 j-slice [32wq,32wq+32): m=k*32+jj
    #pragma unroll
    for (int i = 0; i < 5; ++i) {
        int m = i * 64 + lane;
        W2r[i] = W2[(m >> 5) * 128 + wq * 32 + (m & 31)];
    }
    float W3r = W3[wq * 64 + lane];       // m = 2*jj + c = lane

    const int tile0 = blockIdx.x * NTPB;

    // ---- prologue: stage tile0 -> buf0 ----
    stage_quarter(x + (size_t)tile0 * TILE_F + wq * 4960 + lane * 4,
                  lds + wq * 4960, lane);

    f32x2* pps = (f32x2*)(lds + 2 * TILE_F);        // 256 f32x2 (p partials)
    f32x2* ccs = (f32x2*)(lds + 2 * TILE_F + 512);  // 64 f32x2 (coeffs)

    for (int it = 0; it < NTPB; ++it) {
        const int tile = tile0 + it;
        float* buf = lds + (it & 1) * TILE_F;

        // ---- data_t loads for THIS tile (oldest vm ops of the iter) ----
        const f32x4* dt4 = (const f32x4*)data_t + (size_t)tile * 1600;
        f32x4 tv[7];
        #pragma unroll
        for (int i = 0; i < 7; ++i) {
            int idx = i * 256 + t;
            if (idx < 1600) tv[i] = dt4[idx];
        }

        // ---- stage next tile, counted wait (never 0 mid-loop) ----
        if (it + 1 < NTPB) {
            stage_quarter(x + (size_t)(tile + 1) * TILE_F + wq * 4960 + lane * 4,
                          lds + ((it + 1) & 1) * TILE_F + wq * 4960, lane);
            asm volatile("s_waitcnt vmcnt(20)" ::: "memory");
        } else {
            asm volatile("s_waitcnt vmcnt(0)" ::: "memory");
        }
        __builtin_amdgcn_s_barrier();    // (d) tile `it` fully resident

        // ---- L1: all 64 rows, my k-quarter; W via readlane (no SMEM/DS) ----
        float acc[10] = {0,0,0,0,0,0,0,0,0,0};
        const float* xr = buf + row * 310 + k0;
        #pragma unroll
        for (int kk = 0; kk < 39; ++kk) {
            int off = 2 * kk;
            if (off > KQ - 2) off = KQ - 2;          // wave3 tail clamp (W=0 there)
            f32x2 xp = *(const f32x2*)(xr + off);    // ds_read_b64, own row
            #pragma unroll
            for (int j = 0; j < 10; ++j) {
                int mlo = 20 * kk + j, mhi = 20 * kk + 10 + j;
                acc[j] += xp.x * rlane(Wq[mlo >> 6], mlo & 63)
                        + xp.y * rlane(Wq[mhi >> 6], mhi & 63);
            }
        }

        __builtin_amdgcn_s_barrier();    // (a0) all x reads done -> alias ok

        // ---- write h1 partials [row][wq][10] into consumed x region ----
        {
            float* pw = buf + row * 40 + wq * 10;
            #pragma unroll
            for (int j = 0; j < 5; ++j)
                *(f32x2*)(pw + 2 * j) = (f32x2){acc[2 * j], acc[2 * j + 1]};
        }
        asm volatile("s_waitcnt lgkmcnt(0)" ::: "memory");
        __builtin_amdgcn_s_barrier();    // (a)

        // ---- h1 = leaky(sum of 4 partials + b1), per thread own row ----
        float h1[10];
        {
            const float* pr = buf + row * 40;
            f32x4 P[10];
            #pragma unroll
            for (int i = 0; i < 10; ++i) P[i] = *(const f32x4*)(pr + 4 * i);
            #pragma unroll
            for (int j = 0; j < 10; ++j) {
                float s = P[(j) >> 2][(j) & 3] + P[(10 + j) >> 2][(10 + j) & 3]
                        + P[(20 + j) >> 2][(20 + j) & 3] + P[(30 + j) >> 2][(30 + j) & 3]
                        + b1[j];
                h1[j] = leaky(s);
            }
        }

        // ---- L2 j-slice (32 outs) fused with L3 partial; W via readlane ----
        f32x2 p = {0.f, 0.f};
        #pragma unroll
        for (int jj = 0; jj < 32; ++jj) {
            float s = b2[wq * 32 + jj];
            #pragma unroll
            for (int k = 0; k < 10; ++k) {
                int m = k * 32 + jj;
                s += h1[k] * rlane(W2r[m >> 6], m & 63);
            }
            s = leaky(s);
            p.x += s * rlane(W3r, (2 * jj) & 63);
            p.y += s * rlane(W3r, (2 * jj + 1) & 63);
        }

        // ---- cross-wave coeff reduce via free-region scratch ----
        pps[row * 4 + wq] = p;
        asm volatile("s_waitcnt lgkmcnt(0)" ::: "memory");
        __builtin_amdgcn_s_barrier();    // (b)
        if (t < 64) {
            f32x2 q = pps[t * 4 + 0] + pps[t * 4 + 1] + pps[t * 4 + 2] + pps[t * 4 + 3];
            q.x += b3[0]; q.y += b3[1];
            ccs[t] = leaky2(q);
        }
        asm volatile("s_waitcnt lgkmcnt(0)" ::: "memory");
        __builtin_amdgcn_s_barrier();    // (b2)

        // ---- epilogue: out = t*(c0 + c1*t), coalesced f32x4 ----
        f32x4* o4 = (f32x4*)out + (size_t)tile * 1600;
        #pragma unroll
        for (int i = 0; i < 7; ++i) {
            int idx = i * 256 + t;
            if (idx < 1600) {
                f32x2 cc = ccs[idx / 25];
                f32x4 tt = tv[i];
                o4[idx] = tt * (tt * cc.y + cc.x);
            }
        }
    }
}

extern "C" void kernel_launch(void* const* d_in, const int* in_sizes, int n_in,
                              void* d_out, int out_size, void* d_ws, size_t ws_size,
                              hipStream_t stream) {
    const float* x      = (const float*)d_in[0];
    const float* data_t = (const float*)d_in[1];
    const float* W1     = (const float*)d_in[2];
    const float* b1     = (const float*)d_in[3];
    const float* W2     = (const float*)d_in[4];
    const float* b2     = (const float*)d_in[5];
    const float* W3     = (const float*)d_in[6];
    const float* b3     = (const float*)d_in[7];
    float* out = (float*)d_out;

    // >64 KiB dynamic LDS needs the attribute raised (idempotent, host-side).
    hipFuncSetAttribute((const void*)gen_mlp_r5,
                        hipFuncAttributeMaxDynamicSharedMemorySize, LDS_BYTES);
    // 256 blocks (1 per CU) x 8 tiles of 64 rows = 131072 rows
    gen_mlp_r5<<<256, 256, LDS_BYTES, stream>>>(x, data_t, W1, b1, W2, b2, W3, b3, out);
}

// Round 6
// 74.439 us; speedup vs baseline: 2.6336x; 1.0562x over previous
//
#include <hip/hip_runtime.h>
#include <stdint.h>

typedef float f32x2 __attribute__((ext_vector_type(2)));
typedef float f32x4 __attribute__((ext_vector_type(4)));

#define TILE_F  19840            // 64 rows x 310 floats
#define NTPB    8                // tiles per block
#define PSTR    84               // h1-partial stride (dwords): 84/4=21 odd -> no b128 conflicts
#define LDS_FLOATS (2 * TILE_F + 64 * 18)   // 2 bufs + pps region (stride 18/row: 8 partials + coeff)
#define LDS_BYTES  (LDS_FLOATS * 4)         // 163,328 <= 163,840

__device__ __forceinline__ float leaky(float v) { return fmaxf(v, 0.01f * v); }
__device__ __forceinline__ f32x2 leaky2(f32x2 v) {
    return __builtin_elementwise_max(v, v * 0.01f);
}
__device__ __forceinline__ float rlane(float v, int l) {
    return __uint_as_float(__builtin_amdgcn_readlane(__float_as_uint(v), l));
}

// global->LDS direct, 16 B per lane (1 KB per wave-instr). LDS base wave-uniform.
__device__ __forceinline__ void gload16(const float* g, float* l) {
    auto gp = reinterpret_cast<const float __attribute__((address_space(1)))*>(
        reinterpret_cast<uintptr_t>(g));
    auto lp = reinterpret_cast<float __attribute__((address_space(3)))*>(
        reinterpret_cast<uintptr_t>(l));
    __builtin_amdgcn_global_load_lds(gp, lp, 16, 0, 0);
}

// Stage one wave-eighth of a tile: 2480 floats = 9 full w16 + 176-float tail (44 lanes).
__device__ __forceinline__ void stage_eighth(const float* src, float* dst, int lane) {
    #pragma unroll
    for (int i = 0; i < 9; ++i) gload16(src + i * 256, dst + i * 256);
    if (lane < 44) gload16(src + 9 * 256, dst + 9 * 256);
}

__global__ __launch_bounds__(512, 2) void gen_mlp_r6(
    const float* __restrict__ x, const float* __restrict__ data_t,
    const float* __restrict__ W1, const float* __restrict__ b1,
    const float* __restrict__ W2, const float* __restrict__ b2,
    const float* __restrict__ W3, const float* __restrict__ b3,
    float* __restrict__ out)
{
    extern __shared__ float lds[];

    const int t    = threadIdx.x;
    const int lane = t & 63;
    const int row  = lane;                                    // lane = row (64 rows/tile)
    const int wq   = __builtin_amdgcn_readfirstlane(t >> 6);  // wave 0..7 = k-eighth / j-sixteenth

    // ---- one-time weight preloads into lane-distributed VGPRs ----
    float Wq[7];                       // W1 k-slice [40wq,40wq+40) x 10 -> m=(k-k0)*10+j
    {
        const int wcnt = (wq == 7) ? 300 : 400;
        #pragma unroll
        for (int i = 0; i < 7; ++i) {
            int m = i * 64 + lane;
            Wq[i] = (m < wcnt) ? W1[wq * 400 + m] : 0.f;
        }
    }
    float W2r[3];                      // W2 j-slice [16wq,16wq+16): m = k*16 + jj
    #pragma unroll
    for (int i = 0; i < 3; ++i) {
        int m = i * 64 + lane;
        W2r[i] = (m < 160) ? W2[(m >> 4) * 128 + wq * 16 + (m & 15)] : 0.f;
    }
    float W3r = (lane < 32) ? W3[wq * 32 + lane] : 0.f;   // m = 2*jj + c

    float* pps = lds + 2 * TILE_F;     // [row][18]: slots 0..15 = 8 f32x2 partials, 16..17 = coeff

    const int tile0 = blockIdx.x * NTPB;

    // ---- prologue: stage tile0 -> buf0 ----
    stage_eighth(x + (size_t)tile0 * TILE_F + wq * 2480 + lane * 4,
                 lds + wq * 2480, lane);

    for (int it = 0; it < NTPB; ++it) {
        const int tile = tile0 + it;
        float* buf = lds + (it & 1) * TILE_F;

        // ---- data_t loads for THIS tile (older than stage-next) ----
        const f32x4* dt4 = (const f32x4*)data_t + (size_t)tile * 1600;
        f32x4 tv[4];
        #pragma unroll
        for (int i = 0; i < 4; ++i) {
            int idx = i * 512 + t;
            if (idx < 1600) tv[i] = dt4[idx];
        }

        // ---- stage next tile; counted wait (never 0 mid-loop) ----
        if (it + 1 < NTPB) {
            stage_eighth(x + (size_t)(tile + 1) * TILE_F + wq * 2480 + lane * 4,
                         lds + ((it + 1) & 1) * TILE_F + wq * 2480, lane);
            asm volatile("s_waitcnt vmcnt(10)" ::: "memory");  // tile `it` + tv resident
        } else {
            asm volatile("s_waitcnt vmcnt(0)" ::: "memory");
        }
        __builtin_amdgcn_s_barrier();    // (d)

        // ---- L1: my k-eighth for my row; x batch-hoisted; W via readlane ----
        const float* xr = buf + row * 310 + wq * 40;
        float xk[40];
        #pragma unroll
        for (int q = 0; q < 20; ++q) {
            int off = 2 * q;
            if (wq == 7 && off > 28) off = 28;     // tail clamp; W zero-padded there
            *(f32x2*)&xk[2 * q] = *(const f32x2*)(xr + off);   // ds_read_b64
        }
        float acc[10] = {0,0,0,0,0,0,0,0,0,0};
        #pragma unroll
        for (int k = 0; k < 40; ++k) {
            #pragma unroll
            for (int j = 0; j < 10; ++j) {
                int m = k * 10 + j;
                acc[j] += xk[k] * rlane(Wq[m >> 6], m & 63);
            }
        }

        __builtin_amdgcn_s_barrier();    // (a0) all x reads done -> alias ok

        // ---- write h1 partials [row][wq][10] into consumed x region ----
        {
            float* pw = buf + row * PSTR + wq * 10;
            #pragma unroll
            for (int j = 0; j < 5; ++j)
                *(f32x2*)(pw + 2 * j) = (f32x2){acc[2 * j], acc[2 * j + 1]};
        }
        asm volatile("s_waitcnt lgkmcnt(0)" ::: "memory");
        __builtin_amdgcn_s_barrier();    // (a)

        // ---- h1 = leaky(sum of 8 partials + b1), per thread own row ----
        float h1[10];
        {
            const float* pr = buf + row * PSTR;
            f32x4 P[20];
            #pragma unroll
            for (int i = 0; i < 20; ++i) P[i] = *(const f32x4*)(pr + 4 * i);
            #pragma unroll
            for (int j = 0; j < 10; ++j) {
                float s = b1[j];
                #pragma unroll
                for (int sl = 0; sl < 8; ++sl) {
                    int m = sl * 10 + j;
                    s += P[m >> 2][m & 3];
                }
                h1[j] = leaky(s);
            }
        }

        // ---- L2 j-slice (16 outs) fused with L3 partial; W via readlane ----
        f32x2 p = {0.f, 0.f};
        #pragma unroll
        for (int jj = 0; jj < 16; ++jj) {
            float s = b2[wq * 16 + jj];            // uniform -> s_load
            #pragma unroll
            for (int k = 0; k < 10; ++k) {
                int m = k * 16 + jj;
                s += h1[k] * rlane(W2r[m >> 6], m & 63);
            }
            s = leaky(s);
            p.x += s * rlane(W3r, (2 * jj) & 63);
            p.y += s * rlane(W3r, (2 * jj + 1) & 63);
        }

        // ---- cross-wave coeff reduce (pps stride 18 dwords: 2-way = free) ----
        *(f32x2*)(pps + row * 18 + 2 * wq) = p;
        asm volatile("s_waitcnt lgkmcnt(0)" ::: "memory");
        __builtin_amdgcn_s_barrier();    // (b)
        if (t < 64) {
            const float* pb = pps + t * 18;
            f32x2 q = *(const f32x2*)(pb + 0)  + *(const f32x2*)(pb + 2)
                    + *(const f32x2*)(pb + 4)  + *(const f32x2*)(pb + 6)
                    + *(const f32x2*)(pb + 8)  + *(const f32x2*)(pb + 10)
                    + *(const f32x2*)(pb + 12) + *(const f32x2*)(pb + 14);
            q.x += b3[0]; q.y += b3[1];
            *(f32x2*)(pps + t * 18 + 16) = leaky2(q);
        }
        asm volatile("s_waitcnt lgkmcnt(0)" ::: "memory");
        __builtin_amdgcn_s_barrier();    // (b2)

        // ---- epilogue: out = t*(c0 + c1*t), coalesced f32x4 ----
        f32x4* o4 = (f32x4*)out + (size_t)tile * 1600;
        #pragma unroll
        for (int i = 0; i < 4; ++i) {
            int idx = i * 512 + t;
            if (idx < 1600) {
                f32x2 cc = *(const f32x2*)(pps + (idx / 25) * 18 + 16);
                f32x4 tt = tv[i];
                o4[idx] = tt * (tt * cc.y + cc.x);
            }
        }
    }
}

extern "C" void kernel_launch(void* const* d_in, const int* in_sizes, int n_in,
                              void* d_out, int out_size, void* d_ws, size_t ws_size,
                              hipStream_t stream) {
    const float* x      = (const float*)d_in[0];
    const float* data_t = (const float*)d_in[1];
    const float* W1     = (const float*)d_in[2];
    const float* b1     = (const float*)d_in[3];
    const float* W2     = (const float*)d_in[4];
    const float* b2     = (const float*)d_in[5];
    const float* W3     = (const float*)d_in[6];
    const float* b3     = (const float*)d_in[7];
    float* out = (float*)d_out;

    hipFuncSetAttribute((const void*)gen_mlp_r6,
                        hipFuncAttributeMaxDynamicSharedMemorySize, LDS_BYTES);
    // 256 blocks (1/CU) x 512 threads (8 waves) x 8 tiles of 64 rows = 131072 rows
    gen_mlp_r6<<<256, 512, LDS_BYTES, stream>>>(x, data_t, W1, b1, W2, b2, W3, b3, out);
}

// Round 7
// 70.054 us; speedup vs baseline: 2.7984x; 1.0626x over previous
//
#include <hip/hip_runtime.h>
#include <stdint.h>

typedef float f32x2 __attribute__((ext_vector_type(2)));
typedef float f32x4 __attribute__((ext_vector_type(4)));

#define TILE_F  19840            // 64 rows x 310 floats
#define NTPB    8                // tiles per block
#define PSTR    84               // partial stride (dwords); 84/4=21 odd -> b128 conflict-light
#define LDS_FLOATS (2 * TILE_F + 64 * 18)
#define LDS_BYTES  (LDS_FLOATS * 4)        // 163,328 <= 163,840

__device__ __forceinline__ float leaky(float v) { return fmaxf(v, 0.01f * v); }
__device__ __forceinline__ f32x2 leaky2(f32x2 v) {
    return __builtin_elementwise_max(v, v * 0.01f);
}

// global->LDS direct, 16 B per lane (1 KB per wave-instr). LDS base wave-uniform.
__device__ __forceinline__ void gload16(const float* g, float* l) {
    auto gp = reinterpret_cast<const float __attribute__((address_space(1)))*>(
        reinterpret_cast<uintptr_t>(g));
    auto lp = reinterpret_cast<float __attribute__((address_space(3)))*>(
        reinterpret_cast<uintptr_t>(l));
    __builtin_amdgcn_global_load_lds(gp, lp, 16, 0, 0);
}

// Stage one wave-eighth of a tile: 2480 floats = 9 full w16 + 176-float tail.
__device__ __forceinline__ void stage_eighth(const float* src, float* dst, int lane) {
    #pragma unroll
    for (int i = 0; i < 9; ++i) gload16(src + i * 256, dst + i * 256);
    if (lane < 44) gload16(src + 9 * 256, dst + 9 * 256);
}

// L1 partial: KQ k's of this thread's row; W broadcast from SGPRs (s_load).
template<int KQ>
__device__ __forceinline__ void l1_fma(const float* xr, const float* __restrict__ Wb,
                                       float* acc) {
    float xk[KQ];
    #pragma unroll
    for (int q = 0; q < KQ / 2; ++q)
        *(f32x2*)&xk[2 * q] = *(const f32x2*)(xr + 2 * q);   // ds_read_b64, own row
    #pragma unroll
    for (int k = 0; k < KQ; ++k) {
        #pragma unroll
        for (int j = 0; j < 10; ++j)
            acc[j] += xk[k] * Wb[k * 10 + j];   // v_fmac_f32 with SGPR src
    }
}

__global__ __launch_bounds__(512, 2) void gen_mlp_r7(
    const float* __restrict__ x, const float* __restrict__ data_t,
    const float* __restrict__ W1, const float* __restrict__ b1,
    const float* __restrict__ W2, const float* __restrict__ b2,
    const float* __restrict__ W3, const float* __restrict__ b3,
    float* __restrict__ out)
{
    extern __shared__ float lds[];

    const int t    = threadIdx.x;
    const int lane = t & 63;
    const int row  = lane;                                    // lane = row
    const int wq   = __builtin_amdgcn_readfirstlane(t >> 6);  // wave 0..7

    float* pps = lds + 2 * TILE_F;   // [row][18]: 16 dwords partials, 2 coeff

    const int tile0 = blockIdx.x * NTPB;

    // ---- prologue: stage tile0 + load its data_t ----
    stage_eighth(x + (size_t)tile0 * TILE_F + wq * 2480 + lane * 4,
                 lds + wq * 2480, lane);
    f32x4 tvA[4], tvB[4];
    {
        const f32x4* d0 = (const f32x4*)data_t + (size_t)tile0 * 1600;
        tvA[0] = d0[t]; tvA[1] = d0[512 + t]; tvA[2] = d0[1024 + t];
        tvA[3] = d0[1536 + (t & 63)];
    }

    auto body = [&](int it, f32x4 (&tvc)[4], f32x4 (&tvn)[4]) {
        const int tile = tile0 + it;
        float* buf = lds + (it & 1) * TILE_F;

        // ---- prefetch tile it+1 (x -> LDS, data_t -> regs) ----
        if (it < NTPB - 1) {
            stage_eighth(x + (size_t)(tile + 1) * TILE_F + wq * 2480 + lane * 4,
                         lds + ((it + 1) & 1) * TILE_F + wq * 2480, lane);
            const f32x4* dn = (const f32x4*)data_t + (size_t)(tile + 1) * 1600;
            tvn[0] = dn[t]; tvn[1] = dn[512 + t]; tvn[2] = dn[1024 + t];
            tvn[3] = dn[1536 + (t & 63)];
            // protects only the gload_lds->ds_read hazard: newer-than-stage(it) =
            // tv(it) 4 + stores(it-1) 4 + stage(it+1) 10 + tv(it+1) 4 = 22.
            asm volatile("s_waitcnt vmcnt(22)" ::: "memory");
        } else {
            asm volatile("s_waitcnt vmcnt(8)" ::: "memory");  // tv(7)4+stores(6)4 newer
        }
        __builtin_amdgcn_s_barrier();    // (d) tile `it` resident in LDS

        // ---- L1: my k-eighth, own row; weights via s_load (SGPR) ----
        float acc[10] = {0,0,0,0,0,0,0,0,0,0};
        const float* xr = buf + row * 310 + wq * 40;
        if (wq == 7) l1_fma<30>(xr, W1 + 2800, acc);
        else         l1_fma<40>(xr, W1 + wq * 400, acc);

        __builtin_amdgcn_s_barrier();    // (a0) all x reads done -> alias ok

        {   // partials [row][wq][10] into consumed x region
            float* pw = buf + row * PSTR + wq * 10;
            #pragma unroll
            for (int j = 0; j < 5; ++j)
                *(f32x2*)(pw + 2 * j) = (f32x2){acc[2 * j], acc[2 * j + 1]};
        }
        asm volatile("s_waitcnt lgkmcnt(0)" ::: "memory");
        __builtin_amdgcn_s_barrier();    // (a)

        // ---- h1 = leaky(sum of 8 partials + b1) ----
        float h1[10];
        {
            const float* pr = buf + row * PSTR;
            f32x4 P[20];
            #pragma unroll
            for (int i = 0; i < 20; ++i) P[i] = *(const f32x4*)(pr + 4 * i);
            #pragma unroll
            for (int j = 0; j < 10; ++j) {
                float s = b1[j];
                #pragma unroll
                for (int sl = 0; sl < 8; ++sl) {
                    int m = sl * 10 + j;
                    s += P[m >> 2][m & 3];
                }
                h1[j] = leaky(s);
            }
        }

        // ---- L2 j-slice (16 outs) + L3 partial; all weights via s_load ----
        float hh[16];
        #pragma unroll
        for (int jj = 0; jj < 16; ++jj) hh[jj] = b2[wq * 16 + jj];
        #pragma unroll
        for (int k = 0; k < 10; ++k) {
            #pragma unroll
            for (int jj = 0; jj < 16; ++jj)
                hh[jj] += h1[k] * W2[k * 128 + wq * 16 + jj];   // s_load_dwordx16/k
        }
        f32x2 p = {0.f, 0.f};
        #pragma unroll
        for (int jj = 0; jj < 16; ++jj) {
            float s = leaky(hh[jj]);
            p.x += s * W3[(wq * 16 + jj) * 2 + 0];
            p.y += s * W3[(wq * 16 + jj) * 2 + 1];
        }

        // ---- cross-wave coeff reduce ----
        *(f32x2*)(pps + row * 18 + 2 * wq) = p;
        asm volatile("s_waitcnt lgkmcnt(0)" ::: "memory");
        __builtin_amdgcn_s_barrier();    // (b)
        if (wq == 0) {
            const float* pb = pps + row * 18;
            f32x2 q = *(const f32x2*)(pb + 0)  + *(const f32x2*)(pb + 2)
                    + *(const f32x2*)(pb + 4)  + *(const f32x2*)(pb + 6)
                    + *(const f32x2*)(pb + 8)  + *(const f32x2*)(pb + 10)
                    + *(const f32x2*)(pb + 12) + *(const f32x2*)(pb + 14);
            q.x += b3[0]; q.y += b3[1];
            *(f32x2*)(pps + row * 18 + 16) = leaky2(q);
        }
        asm volatile("s_waitcnt lgkmcnt(0)" ::: "memory");
        __builtin_amdgcn_s_barrier();    // (b2)

        // ---- epilogue: out = t*(c0 + c1*t) ----
        f32x4* o4 = (f32x4*)out + (size_t)tile * 1600;
        #pragma unroll
        for (int i = 0; i < 3; ++i) {
            const int idx = i * 512 + t;
            f32x2 cc = *(const f32x2*)(pps + (idx / 25) * 18 + 16);
            f32x4 tt = tvc[i];
            o4[idx] = tt * (tt * cc.y + cc.x);
        }
        if (t < 64) {
            const int idx = 1536 + t;
            f32x2 cc = *(const f32x2*)(pps + (idx / 25) * 18 + 16);
            f32x4 tt = tvc[3];
            o4[idx] = tt * (tt * cc.y + cc.x);
        }
    };

    #pragma unroll 1
    for (int it2 = 0; it2 < NTPB / 2; ++it2) {
        body(2 * it2,     tvA, tvB);
        body(2 * it2 + 1, tvB, tvA);
    }
}

extern "C" void kernel_launch(void* const* d_in, const int* in_sizes, int n_in,
                              void* d_out, int out_size, void* d_ws, size_t ws_size,
                              hipStream_t stream) {
    const float* x      = (const float*)d_in[0];
    const float* data_t = (const float*)d_in[1];
    const float* W1     = (const float*)d_in[2];
    const float* b1     = (const float*)d_in[3];
    const float* W2     = (const float*)d_in[4];
    const float* b2     = (const float*)d_in[5];
    const float* W3     = (const float*)d_in[6];
    const float* b3     = (const float*)d_in[7];
    float* out = (float*)d_out;

    hipFuncSetAttribute((const void*)gen_mlp_r7,
                        hipFuncAttributeMaxDynamicSharedMemorySize, LDS_BYTES);
    // 256 blocks (1/CU) x 512 threads (8 waves) x 8 tiles of 64 rows = 131072 rows
    gen_mlp_r7<<<256, 512, LDS_BYTES, stream>>>(x, data_t, W1, b1, W2, b2, W3, b3, out);
}